// Round 9
// baseline (153.696 us; speedup 1.0000x reference)
//
#include <hip/hip_runtime.h>

// MSDeformAttn sampling-weight scatter (RankDetr), bug-compatible with the
// reference's axis-mislabeled reshape: output column q' = m/48, m=(l*8+h)*300+q.
//
// R9: BINNED TWO-PHASE SCATTER.
// Ledger: R4 killed output-RMW + NT theories; R6 killed tile-size (occupancy
// must stay 4 blk/CU); R8 killed load-coalescing (82.9 vs 80.6). Remaining
// big term in the non-write phase (~10-14.6us, R5): the scan's 5.3x
// REDUNDANCY -- every sample is re-scanned by all tiles of its level
// (L0 15x, L1 4x): 798 blocks x 96 wave-LDS-atomic-inst = 77K wave-inst for
// 921K useful corner-adds (~14K wave-inst). Binning removes it without
// touching occupancy:
//   A) msda_bin: thread per (s,lv) (coalesced reads), per p emits <=2
//      row-records {ql|cell|cv bits, w_row, fc} into ws bins keyed by
//      (q'-group g, row-tile tb) via device atomicAdd counters (64B-strided).
//      ~460K recs x 16B = 7.4MB. CAP=3072/bin = provable worst case
//      (384 m x 4 p x 2 rows).
//   B) msda_tiled: R0 geometry (21 tiles x 38 groups, 40KB LDS, 4 blk/CU,
//      798-block grid co-resident); scan replaced by reading THIS bin's
//      ~550 contiguous records -> 2 masked LDS atomics each (96 -> ~17
//      wave-atomic-inst/block). Zero/gather/write-out = R0 exactly.
// Predicted: kernel side 18.1 -> ~9-10us + 2 node gaps -> dur 74-78.
// If >=80: redundancy wasn't the cost -> declare structural floor next.
//
// Static shapes: N=1, L=6, Q=300, H=8, Lv=4, P=4; M=14400, TOT=230400.
// spatial: (100,167),(50,84),(25,42),(13,21); lsi = 0,16700,20900,21950.

constexpr int NQ     = 300;
constexpr int QW     = 8;                // q'-group width
constexpr int NG     = 38;               // ceil(300/8)
constexpr int NTILES = 21;               // 15 (L0,R=7) + 4 (L1,R=15) + 1 (L2) + 1 (L3)
constexpr int MAXC   = 1280;             // cells cap: L0 7*167=1169, L1 15*84=1260, L2 1050
constexpr int BLK    = 512;
constexpr int MTOT   = 14400;            // N*L*H*Q
constexpr int NBINS  = NG * NTILES;      // 798
constexpr int CAP    = 3072;             // 384 m * 4 p * 2 rows (exact worst case)
constexpr int CNTSTRIDE = 16;            // one counter per 64B (atomic bank spread)

// ---------------- kernel 0: zero the bin counters ----------------------------
__global__ __launch_bounds__(256)
void msda_zero(unsigned int* __restrict__ cnt) {
    const int i = blockIdx.x * 256 + threadIdx.x;
    if (i < NBINS * CNTSTRIDE) cnt[i] = 0u;
}

// ---------------- kernel A: bin samples by (q'-group, row-tile) --------------
// thread tid = 4*s + lv, s = memory-order sample row (l*300+q)*8+h.
// loc4 reads: 32B/lane consecutive; aw4: 16B/lane consecutive (coalesced).
// Output-order m = (l*8+h)*300+q -> g = m/384, ql = (m/48)%8.
// Per p: corners (c0,c1)x(rr,r1); per valid row r: record into bin
// (g, tile(lv,r)):  meta = cv1<<21 | cv0<<20 | ql<<16 | (cellbase+1),
// w_row = w*(r==rr ? 1-fr : fr), fc.  cellbase = (r-r0t)*W + c0 in [-1,1259].
__global__ __launch_bounds__(256, 8)
void msda_bin(const float4* __restrict__ loc4,
              const float4* __restrict__ aw4,
              float4*       __restrict__ recs,   // [NBINS * CAP]
              unsigned int* __restrict__ cnt) {  // [NBINS * CNTSTRIDE]
    const int tid = blockIdx.x * 256 + threadIdx.x;   // 57600 = 225*256 exact
    const int lv = tid & 3;
    const int s  = tid >> 2;
    const int l  = s / 2400;
    const int rem = s - l * 2400;
    const int q  = rem >> 3;
    const int h  = rem & 7;
    const int m  = (l * 8 + h) * 300 + q;             // output-order index
    const int g  = m / 384;                           // q'-group
    const unsigned ql = (unsigned)((m / 48) & 7);     // local q' in group

    const int W = (lv == 0) ? 167 : (lv == 1) ? 84 : (lv == 2) ? 42 : 21;
    const int H = (lv == 0) ? 100 : (lv == 1) ? 50 : (lv == 2) ? 25 : 13;
    const float fW = (float)W, fH = (float)H;

    const float4 xy01 = loc4[2 * tid];                // (x0,y0,x1,y1)
    const float4 xy23 = loc4[2 * tid + 1];            // (x2,y2,x3,y3)
    const float4 w4   = aw4[tid];                     // (w0,w1,w2,w3)

    const int binbase = g * NTILES;

    #pragma unroll
    for (int p = 0; p < 4; ++p) {
        const float x = (p == 0) ? xy01.x : (p == 1) ? xy01.z : (p == 2) ? xy23.x : xy23.z;
        const float y = (p == 0) ? xy01.y : (p == 1) ? xy01.w : (p == 2) ? xy23.y : xy23.w;
        const float w = (p == 0) ? w4.x   : (p == 1) ? w4.y   : (p == 2) ? w4.z   : w4.w;

        const float cf  = x * fW;
        const float rf  = y * fH;
        const float cfl = floorf(cf), rfl = floorf(rf);
        const float fc  = cf - cfl, fr = rf - rfl;
        const int c0 = (int)cfl, rr = (int)rfl;

        const unsigned cv0 = (unsigned)c0 < (unsigned)W;         // 0 <= c0 < W
        const unsigned cv1 = (unsigned)(c0 + 1) < (unsigned)W;   // 0 <= c0+1 < W
        if (!(cv0 | cv1)) continue;

        #pragma unroll
        for (int e = 0; e < 2; ++e) {
            const int r = rr + e;
            if ((unsigned)r >= (unsigned)H) continue;
            int tb, r0t;
            if (lv == 0)      { tb = r / 7;            r0t = 7  * (r / 7);  }
            else if (lv == 1) { const int t = r / 15;  tb = 15 + t; r0t = 15 * t; }
            else if (lv == 2) { tb = 19; r0t = 0; }
            else              { tb = 20; r0t = 0; }

            const float wrow = w * (e ? fr : (1.0f - fr));
            const int cellbase = (r - r0t) * W + c0;             // [-1, 1259]
            const unsigned meta = (cv1 << 21) | (cv0 << 20) | (ql << 16)
                                | (unsigned)(cellbase + 1);
            const int bin = binbase + tb;
            const unsigned idx = atomicAdd(&cnt[bin * CNTSTRIDE], 1u);
            if (idx < CAP) {                                     // provably always true
                float4 rec;
                rec.x = __int_as_float((int)meta);
                rec.y = wrow;
                rec.z = fc;
                rec.w = 0.f;
                recs[(size_t)bin * CAP + idx] = rec;
            }
        }
    }
}

// ---------------- kernel B: per-(group,tile) LDS accumulate + write-out ------
__global__ __launch_bounds__(BLK, 8)
void msda_tiled(const float4* __restrict__ recs,
                const unsigned int* __restrict__ cnt,
                float* __restrict__ out) {        // (S, NQ)
    __shared__ float sm[QW * MAXC];               // 40,960 B, ql-major

    const int b  = blockIdx.x;
    const int g  = b / NTILES;                    // q'-group 0..37
    const int tb = b % NTILES;                    // s-tile id

    int lv, r0t, nr;
    if (tb < 15)      { lv = 0; r0t = 7  * tb;        nr = min(7,  100 - r0t); }
    else if (tb < 19) { lv = 1; r0t = 15 * (tb - 15); nr = min(15, 50  - r0t); }
    else if (tb < 20) { lv = 2; r0t = 0;              nr = 25; }
    else              { lv = 3; r0t = 0;              nr = 13; }

    const int Wlv_[4] = {167, 84, 42, 21};
    const int lsi_[4] = {0, 16700, 20900, 21950};
    const int W    = Wlv_[lv];
    const int base = lsi_[lv];
    const int g0   = g * QW;
    const int qw   = min(QW, NQ - g0);            // 8, or 4 for the last group
    const int cells = nr * W;
    const int tid  = threadIdx.x;

    const int bin = g * NTILES + tb;
    const int n   = min((int)cnt[bin * CNTSTRIDE], CAP);   // broadcast load
    const float4* myrec = recs + (size_t)bin * CAP;

    // zero the used LDS rows (qw full rows), float4 stores
    {
        const int nz = qw * (MAXC / 4);
        float4* sm4 = (float4*)sm;
        for (int i = tid; i < nz; i += BLK) sm4[i] = make_float4(0.f, 0.f, 0.f, 0.f);
    }
    __syncthreads();

    // accumulate this bin's records: ~550 avg, contiguous float4 reads,
    // 2 masked LDS atomics each (5.3x fewer wave-atomic-inst than the scan).
    for (int i = tid; i < n; i += BLK) {
        const float4 rec = myrec[i];
        const unsigned meta = (unsigned)__float_as_int(rec.x);
        const int cell = (int)(meta & 0xFFFFu) - 1;
        float* smq = &sm[((meta >> 16) & 7u) * MAXC];
        const float wrow = rec.y, fc = rec.z;
        if (meta & (1u << 20)) atomicAdd(&smq[cell],     wrow * (1.0f - fc));
        if (meta & (1u << 21)) atomicAdd(&smq[cell + 1], wrow * fc);
    }
    __syncthreads();

    // write-out: s in [base + r0t*W, +cells), q' in [g0, g0+qw).
    // One float4 global store per (cell, v); LDS gathers are 2 lanes/bank
    // (free per m136). L2 merges the 32B partial-line stores (R4 falsified
    // the RMW theory; NT stores were 2.4x worse).
    const int s0  = base + r0t * W;
    const int nq4 = qw >> 2;                      // 2 (or 1 last group)
    for (int i = tid; i < cells * nq4; i += BLK) {
        const int cell = i / nq4;
        const int v    = i - cell * nq4;
        float4 val;
        val.x = sm[(v * 4 + 0) * MAXC + cell];
        val.y = sm[(v * 4 + 1) * MAXC + cell];
        val.z = sm[(v * 4 + 2) * MAXC + cell];
        val.w = sm[(v * 4 + 3) * MAXC + cell];
        *(float4*)&out[(s0 + cell) * NQ + g0 + v * 4] = val;
    }
}

extern "C" void kernel_launch(void* const* d_in, const int* in_sizes, int n_in,
                              void* d_out, int out_size, void* d_ws, size_t ws_size,
                              hipStream_t stream) {
    const float4* loc4 = (const float4*)d_in[0];  // sampling_locations (fp32), 16B-aligned
    const float4* aw4  = (const float4*)d_in[1];  // attention_weights  (fp32), 16B-aligned
    float* out = (float*)d_out;

    // ws layout: records [NBINS*CAP*16B = 39.2MB] then counters [798*64B].
    float4* recs = (float4*)d_ws;
    unsigned int* cnt = (unsigned int*)((char*)d_ws + (size_t)NBINS * CAP * 16);

    msda_zero<<<(NBINS * CNTSTRIDE + 255) / 256, 256, 0, stream>>>(cnt);
    msda_bin<<<(MTOT * 4) / 256, 256, 0, stream>>>(loc4, aw4, recs, cnt);
    msda_tiled<<<NG * NTILES, BLK, 0, stream>>>(recs, cnt, out);
}